// Round 8
// baseline (148.853 us; speedup 1.0000x reference)
//
#include <hip/hip_runtime.h>
#include <hip/hip_bf16.h>
#include <math.h>

typedef __hip_bfloat16 bf16;
typedef __attribute__((ext_vector_type(8))) short v8s;   // 8 x bf16
typedef __attribute__((ext_vector_type(4))) short v4s;   // 4 x bf16 (8 B)
typedef __attribute__((ext_vector_type(4))) float v4f;

#define HD 96
#define WD 96
#define HW 9216            // 96*96
#define BATCH 4
#define NPIX (BATCH * HW)  // 36864

// ws float-offset layout
#define OFF_WR    0        // 16x64  scaled w_reduce
#define OFF_CR    1024     // 16     reduce-BN additive
#define OFF_WSP   1040     // 196x16 w_span
#define OFF_BSP   4176     // 196    b_span
#define OFF_SI    4372     // 64     bn_i scale
#define OFF_CI    4436     // 64     bn_i additive
#define OFF_BIAS  4500     // 128    combined bias (fp32)
#define WFRAG_BYTE 18512   // bf16 W MFMA A-fragments: [mt8][ks4][lane64][j8] (32KB)
#define TG_BYTE   51328    // bf16 t buffer [NPIX][16] (1.18 MB)
#define ZT_BYTE   1230976  // bf16 zt buffer [NPIX][128]: ch0-63=x1, ch64-127=bf16(x)

__device__ __forceinline__ float geluf(float v) {
    return 0.5f * v * (1.0f + erff(v * 0.7071067811865475f));
}
__device__ __forceinline__ float upbf(short s) {
    unsigned int uu = ((unsigned int)(unsigned short)s) << 16;
    return __builtin_bit_cast(float, uu);
}
__device__ __forceinline__ v4f up4(v4s s) {
    v4f r;
    #pragma unroll
    for (int i = 0; i < 4; ++i) r[i] = upbf(s[i]);
    return r;
}
__device__ __forceinline__ short pkbf(float f) {
    return (short)__bfloat16_as_ushort(__float2bfloat16(f));
}

// ---------------- K0: param fold (blocks 0-63) + t-GEMM (blocks 64-639) ----
__global__ __launch_bounds__(256) void k_pre(
    const float* __restrict__ x,
    const float* __restrict__ wred,
    const float* __restrict__ gr, const float* __restrict__ br,
    const float* __restrict__ mr, const float* __restrict__ vr,
    const float* __restrict__ wspan, const float* __restrict__ bspan,
    const float* __restrict__ gi, const float* __restrict__ bi,
    const float* __restrict__ mi, const float* __restrict__ vi,
    const float* __restrict__ wconv,
    const float* __restrict__ gc, const float* __restrict__ bc,
    const float* __restrict__ mc, const float* __restrict__ vc,
    const float* __restrict__ wmap, const float* __restrict__ bmap,
    const float* __restrict__ gm, const float* __restrict__ bm,
    const float* __restrict__ mmn, const float* __restrict__ vm,
    float* __restrict__ wsf, bf16* __restrict__ wfrag, bf16* __restrict__ tg)
{
    const int tid = threadIdx.x;
    const int blk = blockIdx.x;

    if (blk < 64) {
        const int gt = blk * 256 + tid;   // 0..16383
        if (gt < 1024) {
            int r = gt >> 6;
            float sr = gr[r] * rsqrtf(vr[r] + 1e-5f);
            wsf[OFF_WR + gt] = sr * wred[gt];
        }
        if (gt < 16) {
            float sr = gr[gt] * rsqrtf(vr[gt] + 1e-5f);
            wsf[OFF_CR + gt] = br[gt] - mr[gt] * sr;
        }
        if (gt < 3136) wsf[OFF_WSP + gt] = wspan[gt];
        if (gt < 196)  wsf[OFF_BSP + gt] = bspan[gt];
        if (gt < 64) {
            float si = gi[gt] * rsqrtf(vi[gt] + 1e-5f);
            wsf[OFF_SI + gt] = si;
            wsf[OFF_CI + gt] = bi[gt] - mi[gt] * si;
        }
        if (gt < 128) {
            float sc = gc[gt] * rsqrtf(vc[gt] + 1e-5f);
            float sm = gm[gt] * rsqrtf(vm[gt] + 1e-5f);
            wsf[OFF_BIAS + gt] = (bc[gt] - mc[gt] * sc)
                               + sm * bmap[gt]
                               + (bm[gt] - mmn[gt] * sm);
        }
        // W MFMA A-fragments: lane l holds W[mt*16+(l&15)][ks*32+(l>>4)*8+j]
        {
            int j    = gt & 7;
            int lane = (gt >> 3) & 63;
            int ks   = (gt >> 9) & 3;
            int mt   = gt >> 11;
            int m = mt * 16 + (lane & 15);
            int k = ks * 32 + (lane >> 4) * 8 + j;
            float v;
            if (k < 64) {
                float sc = gc[m] * rsqrtf(vc[m] + 1e-5f);
                v = sc * wconv[m * 64 + k];
            } else {
                float sm = gm[m] * rsqrtf(vm[m] + 1e-5f);
                v = sm * wmap[m * 64 + (k - 64)];
            }
            wfrag[gt] = __float2bfloat16(v);
        }
        return;
    }

    // ---- t = ReLU(BN(w_reduce · x)), once per pixel -> tg[px][16] bf16 ----
    __shared__ float wrl[1024];
    __shared__ float crl[16];
    for (int i = tid; i < 1024; i += 256) {
        int r = i >> 6;
        wrl[i] = gr[r] * rsqrtf(vr[r] + 1e-5f) * wred[i];
    }
    if (tid < 16)
        crl[tid] = br[tid] - mr[tid] * gr[tid] * rsqrtf(vr[tid] + 1e-5f);
    __syncthreads();

    const int p = tid & 63, u = tid >> 6;
    const int gpix = (blk - 64) * 64 + p;            // 64-aligned, no b straddle
    const int b = gpix / HW, hw = gpix % HW;
    const float* xb = x + (size_t)b * 64 * HW + hw;

    float t4[4];
    #pragma unroll
    for (int r = 0; r < 4; ++r) t4[r] = crl[u * 4 + r];
    #pragma unroll 4
    for (int c4 = 0; c4 < 16; ++c4) {
        float xc0 = xb[(size_t)(c4 * 4 + 0) * HW];
        float xc1 = xb[(size_t)(c4 * 4 + 1) * HW];
        float xc2 = xb[(size_t)(c4 * 4 + 2) * HW];
        float xc3 = xb[(size_t)(c4 * 4 + 3) * HW];
        #pragma unroll
        for (int r = 0; r < 4; ++r) {
            v4f w = *(const v4f*)&wrl[(u * 4 + r) * 64 + c4 * 4];
            t4[r] += w[0] * xc0 + w[1] * xc1 + w[2] * xc2 + w[3] * xc3;
        }
    }
    v4s pk;
    #pragma unroll
    for (int r = 0; r < 4; ++r) pk[r] = pkbf(fmaxf(t4[r], 0.0f));
    *(v4s*)((short*)tg + (size_t)gpix * 16 + u * 4) = pk;
}

// ---------------- K1: involution + bn_i + GELU -> zt (B-frag layout) -------
// Block: 256 threads = 64 pixels (8x8 tile) x 4 channel-quads of ONE group.
// Grid (12,12,16), z = b*4 + g.  LDS 18.8 KB (bf16 halo) -> 8 blocks/CU.
__global__ __launch_bounds__(256) void k_inv3(
    const float* __restrict__ x, const float* __restrict__ wsf,
    const bf16* __restrict__ tg, bf16* __restrict__ zt)
{
    __shared__ v4s   xh[4 * 196];   // [quad4][pos196] bf16x4    6272 B
    __shared__ float ksh[49 * 64];  // [kk][px]                 12544 B

    const int tid = threadIdx.x;
    const int bz  = blockIdx.z;
    const int b   = bz >> 2, g = bz & 3;
    const int ty  = blockIdx.y * 8, tx = blockIdx.x * 8;

    const float* xb = x + (size_t)b * 64 * HW;

    // ---- stage own-group 14x14 halo (16 ch, bf16 interleaved-4) ----
    for (int it = tid; it < 784; it += 256) {        // it = qc*196 + pos
        int qc = it / 196, pos = it % 196;
        int py = pos / 14, px = pos % 14;
        int gy = ty + py - 3, gx = tx + px - 3;
        v4s v = (v4s){0, 0, 0, 0};
        if (gy >= 0 && gy < HD && gx >= 0 && gx < WD) {
            const float* pp = xb + (size_t)(g * 16 + qc * 4) * HW + gy * WD + gx;
            v[0] = pkbf(pp[0]);
            v[1] = pkbf(pp[HW]);
            v[2] = pkbf(pp[2 * HW]);
            v[3] = pkbf(pp[3 * HW]);
        }
        xh[it] = v;
    }

    // ---- kern (independent of halo): read t, compute ksh ----
    const int p  = tid & 63;
    const int u  = __builtin_amdgcn_readfirstlane(tid >> 6);  // wave-uniform
    const int py0 = p >> 3, px0 = p & 7;
    const int hw  = (ty + py0) * WD + (tx + px0);
    const int gpix = b * HW + hw;

    const v8s* tp = (const v8s*)((const short*)tg + (size_t)gpix * 16);
    v8s t01 = tp[0], t23 = tp[1];
    float tr[16];
    #pragma unroll
    for (int i = 0; i < 8; ++i) { tr[i] = upbf(t01[i]); tr[8 + i] = upbf(t23[i]); }

    for (int kk = u; kk < 49; kk += 4) {
        int row = g * 49 + kk;                       // wave-uniform -> s_load
        float kv = wsf[OFF_BSP + row];
        #pragma unroll
        for (int r = 0; r < 16; ++r) kv += wsf[OFF_WSP + row * 16 + r] * tr[r];
        ksh[kk * 64 + p] = kv;
    }
    __syncthreads();

    // ---- involution accumulate: 4 channels per thread ----
    float acc[4] = {0.f, 0.f, 0.f, 0.f};
    #pragma unroll 1
    for (int i = 0; i < 7; ++i) {
        const int rowb = (py0 + i) * 14 + px0;
        #pragma unroll
        for (int j = 0; j < 7; ++j) {
            float kv = ksh[(i * 7 + j) * 64 + p];
            v4f xv = up4(xh[u * 196 + rowb + j]);
            acc[0] += kv * xv[0];
            acc[1] += kv * xv[1];
            acc[2] += kv * xv[2];
            acc[3] += kv * xv[3];
        }
    }

    // ---- bn_i + GELU, pack into zt B-fragment layout ----
    const int c0 = g * 16 + u * 4;
    bf16* ztr = zt + ((size_t)b * HW + hw) * 128;

    v4s pk1;
    #pragma unroll
    for (int ci = 0; ci < 4; ++ci) {
        float v = acc[ci] * wsf[OFF_SI + c0 + ci] + wsf[OFF_CI + c0 + ci];
        pk1[ci] = pkbf(geluf(v));
    }
    *(v4s*)&ztr[c0] = pk1;

    const int center = (py0 + 3) * 14 + (px0 + 3);
    *(v4s*)&ztr[64 + c0] = xh[u * 196 + center];   // already bf16-rounded
}

// ---------------- K2: 128x128 pointwise GEMM + GELU via MFMA ---------------
// Block: 256 threads = 4 waves over SAME 16 px; wave mq covers 32 out rows.
// Grid 2304 -> 9216 waves (36/CU).
__global__ __launch_bounds__(256) void k_out3(
    const bf16* __restrict__ zt, const float* __restrict__ wsf,
    const bf16* __restrict__ wfrag, float* __restrict__ out)
{
    const int tid  = threadIdx.x;
    const int lane = tid & 63;
    const int mq   = tid >> 6;             // 0..3: which 32-row chunk
    const int n    = lane & 15;
    const int quad = lane >> 4;

    const int pxg = blockIdx.x * 16 + n;   // global pixel
    const int b   = pxg / HW;
    const int hw  = pxg % HW;

    const v8s* zb = (const v8s*)(zt + (size_t)pxg * 128);
    v8s bfr[4];
    #pragma unroll
    for (int ki = 0; ki < 4; ++ki) bfr[ki] = zb[ki * 4 + quad];

    const v8s* wf = (const v8s*)wfrag;
    v4f acc[2];
    acc[0] = (v4f){0.f, 0.f, 0.f, 0.f};
    acc[1] = (v4f){0.f, 0.f, 0.f, 0.f};

    #pragma unroll
    for (int ki = 0; ki < 4; ++ki) {
        #pragma unroll
        for (int m = 0; m < 2; ++m) {
            int mt = mq * 2 + m;
            v8s afrag = wf[(mt * 4 + ki) * 64 + lane];
            acc[m] = __builtin_amdgcn_mfma_f32_16x16x32_bf16(afrag, bfr[ki], acc[m], 0, 0, 0);
        }
    }

    #pragma unroll
    for (int m = 0; m < 2; ++m) {
        int m0 = (mq * 2 + m) * 16 + quad * 4;
        v4f bs = *(const v4f*)&wsf[OFF_BIAS + m0];
        #pragma unroll
        for (int reg = 0; reg < 4; ++reg) {
            float v = acc[m][reg] + bs[reg];
            out[((size_t)(b * 128 + m0 + reg)) * HW + hw] = geluf(v);
        }
    }
}

// ---------------------------------------------------------------------------
extern "C" void kernel_launch(void* const* d_in, const int* in_sizes, int n_in,
                              void* d_out, int out_size, void* d_ws, size_t ws_size,
                              hipStream_t stream)
{
    const float* x     = (const float*)d_in[0];
    const float* wred  = (const float*)d_in[1];
    const float* gr    = (const float*)d_in[2];
    const float* br    = (const float*)d_in[3];
    const float* mr    = (const float*)d_in[4];
    const float* vr    = (const float*)d_in[5];
    const float* wspan = (const float*)d_in[6];
    const float* bspan = (const float*)d_in[7];
    const float* gi    = (const float*)d_in[8];
    const float* bi    = (const float*)d_in[9];
    const float* mi    = (const float*)d_in[10];
    const float* vi    = (const float*)d_in[11];
    const float* wconv = (const float*)d_in[12];
    const float* gc    = (const float*)d_in[13];
    const float* bc    = (const float*)d_in[14];
    const float* mc    = (const float*)d_in[15];
    const float* vc    = (const float*)d_in[16];
    const float* wmap  = (const float*)d_in[17];
    const float* bmap  = (const float*)d_in[18];
    const float* gm    = (const float*)d_in[19];
    const float* bm    = (const float*)d_in[20];
    const float* mmn   = (const float*)d_in[21];
    const float* vm    = (const float*)d_in[22];

    float* wsf   = (float*)d_ws;
    bf16*  wfrag = (bf16*)((char*)d_ws + WFRAG_BYTE);
    bf16*  tg    = (bf16*)((char*)d_ws + TG_BYTE);
    bf16*  zt    = (bf16*)((char*)d_ws + ZT_BYTE);
    float* out   = (float*)d_out;

    hipLaunchKernelGGL(k_pre, dim3(64 + NPIX / 64), dim3(256), 0, stream,
                       x, wred, gr, br, mr, vr, wspan, bspan, gi, bi, mi, vi,
                       wconv, gc, bc, mc, vc, wmap, bmap, gm, bm, mmn, vm,
                       wsf, wfrag, tg);
    hipLaunchKernelGGL(k_inv3, dim3(12, 12, 16), dim3(256), 0, stream,
                       x, wsf, tg, zt);
    hipLaunchKernelGGL(k_out3, dim3(NPIX / 16), dim3(256), 0, stream,
                       zt, wsf, wfrag, out);
}

// Round 9
// 144.180 us; speedup vs baseline: 1.0324x; 1.0324x over previous
//
#include <hip/hip_runtime.h>
#include <hip/hip_bf16.h>
#include <math.h>

typedef __hip_bfloat16 bf16;
typedef __attribute__((ext_vector_type(8))) short v8s;   // 8 x bf16
typedef __attribute__((ext_vector_type(4))) short v4s;   // 4 x bf16 (8 B)
typedef __attribute__((ext_vector_type(4))) float v4f;

#define HD 96
#define WD 96
#define HW 9216            // 96*96
#define BATCH 4
#define NPIX (BATCH * HW)  // 36864

// ws layout
#define OFF_WR    0        // 16x64  scaled w_reduce (fp32)
#define OFF_CR    1024     // 16     reduce-BN additive
#define OFF_WSP   1040     // 196x16 w_span
#define OFF_BSP   4176     // 196    b_span
#define OFF_SI    4372     // 64     bn_i scale
#define OFF_CI    4436     // 64     bn_i additive
#define OFF_BIAS  4500     // 128    combined bias (fp32)
#define WFRAG_BYTE 18512   // bf16 W MFMA A-frags [mt8][ks4][lane64][j8] (32KB)
#define TG_BYTE   51328    // bf16 t buffer [NPIX][16] (1.18 MB)
#define ZT_BYTE   1230976  // bf16 zt [NPIX][128] (9.44 MB)
#define XBF_BYTE  10668160 // bf16 x copy [b][cq16][hw][4] (4.72 MB)

__device__ __forceinline__ float geluf(float v) {
    return 0.5f * v * (1.0f + erff(v * 0.7071067811865475f));
}
__device__ __forceinline__ float upbf(short s) {
    unsigned int uu = ((unsigned int)(unsigned short)s) << 16;
    return __builtin_bit_cast(float, uu);
}
__device__ __forceinline__ v4f up4(v4s s) {
    v4f r;
    #pragma unroll
    for (int i = 0; i < 4; ++i) r[i] = upbf(s[i]);
    return r;
}
__device__ __forceinline__ short pkbf(float f) {
    return (short)__bfloat16_as_ushort(__float2bfloat16(f));
}

// ---------------- K0: param fold (blocks 0-63) + t-GEMM + xbf copy ---------
__global__ __launch_bounds__(256) void k_pre(
    const float* __restrict__ x,
    const float* __restrict__ wred,
    const float* __restrict__ gr, const float* __restrict__ br,
    const float* __restrict__ mr, const float* __restrict__ vr,
    const float* __restrict__ wspan, const float* __restrict__ bspan,
    const float* __restrict__ gi, const float* __restrict__ bi,
    const float* __restrict__ mi, const float* __restrict__ vi,
    const float* __restrict__ wconv,
    const float* __restrict__ gc, const float* __restrict__ bc,
    const float* __restrict__ mc, const float* __restrict__ vc,
    const float* __restrict__ wmap, const float* __restrict__ bmap,
    const float* __restrict__ gm, const float* __restrict__ bm,
    const float* __restrict__ mmn, const float* __restrict__ vm,
    float* __restrict__ wsf, bf16* __restrict__ wfrag,
    bf16* __restrict__ tg, v4s* __restrict__ xbf)
{
    const int tid = threadIdx.x;
    const int blk = blockIdx.x;

    if (blk < 64) {
        const int gt = blk * 256 + tid;   // 0..16383
        if (gt < 1024) {
            int r = gt >> 6;
            float sr = gr[r] * rsqrtf(vr[r] + 1e-5f);
            wsf[OFF_WR + gt] = sr * wred[gt];
        }
        if (gt < 16) {
            float sr = gr[gt] * rsqrtf(vr[gt] + 1e-5f);
            wsf[OFF_CR + gt] = br[gt] - mr[gt] * sr;
        }
        if (gt < 3136) wsf[OFF_WSP + gt] = wspan[gt];
        if (gt < 196)  wsf[OFF_BSP + gt] = bspan[gt];
        if (gt < 64) {
            float si = gi[gt] * rsqrtf(vi[gt] + 1e-5f);
            wsf[OFF_SI + gt] = si;
            wsf[OFF_CI + gt] = bi[gt] - mi[gt] * si;
        }
        if (gt < 128) {
            float sc = gc[gt] * rsqrtf(vc[gt] + 1e-5f);
            float sm = gm[gt] * rsqrtf(vm[gt] + 1e-5f);
            wsf[OFF_BIAS + gt] = (bc[gt] - mc[gt] * sc)
                               + sm * bmap[gt]
                               + (bm[gt] - mmn[gt] * sm);
        }
        // W MFMA A-fragments: lane l holds W[mt*16+(l&15)][ks*32+(l>>4)*8+j]
        {
            int j    = gt & 7;
            int lane = (gt >> 3) & 63;
            int ks   = (gt >> 9) & 3;
            int mt   = gt >> 11;
            int m = mt * 16 + (lane & 15);
            int k = ks * 32 + (lane >> 4) * 8 + j;
            float v;
            if (k < 64) {
                float sc = gc[m] * rsqrtf(vc[m] + 1e-5f);
                v = sc * wconv[m * 64 + k];
            } else {
                float sm = gm[m] * rsqrtf(vm[m] + 1e-5f);
                v = sm * wmap[m * 64 + (k - 64)];
            }
            wfrag[gt] = __float2bfloat16(v);
        }
        return;
    }

    // ---- t = ReLU(BN(w_reduce · x)) per pixel; also emit bf16 x copy ----
    __shared__ float wrl[1024];
    __shared__ float crl[16];
    for (int i = tid; i < 1024; i += 256) {
        int r = i >> 6;
        wrl[i] = gr[r] * rsqrtf(vr[r] + 1e-5f) * wred[i];
    }
    if (tid < 16)
        crl[tid] = br[tid] - mr[tid] * gr[tid] * rsqrtf(vr[tid] + 1e-5f);
    __syncthreads();

    const int p = tid & 63, u = tid >> 6;     // u wave-uniform
    const int gpix = (blk - 64) * 64 + p;     // 64-aligned, no b straddle
    const int b = gpix / HW, hw = gpix % HW;
    const float* xb = x + (size_t)b * 64 * HW + hw;
    v4s* xbf_b = xbf + (size_t)b * 16 * HW;

    float t4[4];
    #pragma unroll
    for (int r = 0; r < 4; ++r) t4[r] = crl[u * 4 + r];
    #pragma unroll 4
    for (int c4 = 0; c4 < 16; ++c4) {
        float xc0 = xb[(size_t)(c4 * 4 + 0) * HW];
        float xc1 = xb[(size_t)(c4 * 4 + 1) * HW];
        float xc2 = xb[(size_t)(c4 * 4 + 2) * HW];
        float xc3 = xb[(size_t)(c4 * 4 + 3) * HW];
        #pragma unroll
        for (int r = 0; r < 4; ++r) {
            v4f w = *(const v4f*)&wrl[(u * 4 + r) * 64 + c4 * 4];
            t4[r] += w[0] * xc0 + w[1] * xc1 + w[2] * xc2 + w[3] * xc3;
        }
        if ((c4 >> 2) == u) {                 // wave-uniform: this wave owns c4
            v4s xv;
            xv[0] = pkbf(xc0); xv[1] = pkbf(xc1);
            xv[2] = pkbf(xc2); xv[3] = pkbf(xc3);
            xbf_b[(size_t)c4 * HW + hw] = xv;
        }
    }
    v4s pk;
    #pragma unroll
    for (int r = 0; r < 4; ++r) pk[r] = pkbf(fmaxf(t4[r], 0.0f));
    *(v4s*)((short*)tg + (size_t)gpix * 16 + u * 4) = pk;
}

// ---------------- K1: involution + bn_i + GELU -> zt (B-frag layout) -------
// Block: 256 threads = 64 pixels (8x8 tile) x 4 channel-quads of ONE group.
// Grid (12,12,16). Halo staged from pre-packed bf16 xbf: pure b64 copies.
__global__ __launch_bounds__(256) void k_inv3(
    const v4s* __restrict__ xbf, const float* __restrict__ wsf,
    const bf16* __restrict__ tg, bf16* __restrict__ zt)
{
    __shared__ v4s   xh[4 * 196];   // [quad4][pos196] bf16x4    6272 B
    __shared__ float ksh[49 * 64];  // [kk][px]                 12544 B

    const int tid = threadIdx.x;
    const int bz  = blockIdx.z;
    const int b   = bz >> 2, g = bz & 3;
    const int ty  = blockIdx.y * 8, tx = blockIdx.x * 8;

    const v4s* xbf_b = xbf + (size_t)b * 16 * HW;

    // ---- stage own-group 14x14 halo: direct b64 copies ----
    for (int it = tid; it < 784; it += 256) {        // it = qc*196 + pos
        int qc = it / 196, pos = it % 196;
        int py = pos / 14, px = pos % 14;
        int gy = ty + py - 3, gx = tx + px - 3;
        v4s v = (v4s){0, 0, 0, 0};
        if (gy >= 0 && gy < HD && gx >= 0 && gx < WD)
            v = xbf_b[(size_t)(g * 4 + qc) * HW + gy * WD + gx];
        xh[it] = v;
    }

    // ---- kern (independent of halo): read t, compute ksh ----
    const int p  = tid & 63;
    const int u  = __builtin_amdgcn_readfirstlane(tid >> 6);  // wave-uniform
    const int py0 = p >> 3, px0 = p & 7;
    const int hw  = (ty + py0) * WD + (tx + px0);
    const int gpix = b * HW + hw;

    const v8s* tp = (const v8s*)((const short*)tg + (size_t)gpix * 16);
    v8s t01 = tp[0], t23 = tp[1];
    float tr[16];
    #pragma unroll
    for (int i = 0; i < 8; ++i) { tr[i] = upbf(t01[i]); tr[8 + i] = upbf(t23[i]); }

    for (int kk = u; kk < 49; kk += 4) {
        int row = g * 49 + kk;                       // wave-uniform -> s_load
        float kv = wsf[OFF_BSP + row];
        #pragma unroll
        for (int r = 0; r < 16; ++r) kv += wsf[OFF_WSP + row * 16 + r] * tr[r];
        ksh[kk * 64 + p] = kv;
    }
    __syncthreads();

    // ---- involution accumulate: 4 channels per thread ----
    float acc[4] = {0.f, 0.f, 0.f, 0.f};
    #pragma unroll 1
    for (int i = 0; i < 7; ++i) {
        const int rowb = (py0 + i) * 14 + px0;
        #pragma unroll
        for (int j = 0; j < 7; ++j) {
            float kv = ksh[(i * 7 + j) * 64 + p];
            v4f xv = up4(xh[u * 196 + rowb + j]);
            acc[0] += kv * xv[0];
            acc[1] += kv * xv[1];
            acc[2] += kv * xv[2];
            acc[3] += kv * xv[3];
        }
    }

    // ---- bn_i + GELU, pack into zt B-fragment layout ----
    const int c0 = g * 16 + u * 4;
    bf16* ztr = zt + ((size_t)b * HW + hw) * 128;

    v4s pk1;
    #pragma unroll
    for (int ci = 0; ci < 4; ++ci) {
        float v = acc[ci] * wsf[OFF_SI + c0 + ci] + wsf[OFF_CI + c0 + ci];
        pk1[ci] = pkbf(geluf(v));
    }
    *(v4s*)&ztr[c0] = pk1;
    *(v4s*)&ztr[64 + c0] = xh[u * 196 + (py0 + 3) * 14 + (px0 + 3)];
}

// ---------------- K2: 128x128 pointwise GEMM + GELU via MFMA ---------------
// Block: 256 threads = 4 waves over SAME 16 px; wave mq covers 32 out rows.
__global__ __launch_bounds__(256) void k_out3(
    const bf16* __restrict__ zt, const float* __restrict__ wsf,
    const bf16* __restrict__ wfrag, float* __restrict__ out)
{
    const int tid  = threadIdx.x;
    const int lane = tid & 63;
    const int mq   = tid >> 6;             // 0..3: which 32-row chunk
    const int n    = lane & 15;
    const int quad = lane >> 4;

    const int pxg = blockIdx.x * 16 + n;   // global pixel
    const int b   = pxg / HW;
    const int hw  = pxg % HW;

    const v8s* zb = (const v8s*)(zt + (size_t)pxg * 128);
    v8s bfr[4];
    #pragma unroll
    for (int ki = 0; ki < 4; ++ki) bfr[ki] = zb[ki * 4 + quad];

    const v8s* wf = (const v8s*)wfrag;
    v4f acc[2];
    acc[0] = (v4f){0.f, 0.f, 0.f, 0.f};
    acc[1] = (v4f){0.f, 0.f, 0.f, 0.f};

    #pragma unroll
    for (int ki = 0; ki < 4; ++ki) {
        #pragma unroll
        for (int m = 0; m < 2; ++m) {
            int mt = mq * 2 + m;
            v8s afrag = wf[(mt * 4 + ki) * 64 + lane];
            acc[m] = __builtin_amdgcn_mfma_f32_16x16x32_bf16(afrag, bfr[ki], acc[m], 0, 0, 0);
        }
    }

    #pragma unroll
    for (int m = 0; m < 2; ++m) {
        int m0 = (mq * 2 + m) * 16 + quad * 4;
        v4f bs = *(const v4f*)&wsf[OFF_BIAS + m0];
        #pragma unroll
        for (int reg = 0; reg < 4; ++reg) {
            float v = acc[m][reg] + bs[reg];
            out[((size_t)(b * 128 + m0 + reg)) * HW + hw] = geluf(v);
        }
    }
}

// ---------------------------------------------------------------------------
extern "C" void kernel_launch(void* const* d_in, const int* in_sizes, int n_in,
                              void* d_out, int out_size, void* d_ws, size_t ws_size,
                              hipStream_t stream)
{
    const float* x     = (const float*)d_in[0];
    const float* wred  = (const float*)d_in[1];
    const float* gr    = (const float*)d_in[2];
    const float* br    = (const float*)d_in[3];
    const float* mr    = (const float*)d_in[4];
    const float* vr    = (const float*)d_in[5];
    const float* wspan = (const float*)d_in[6];
    const float* bspan = (const float*)d_in[7];
    const float* gi    = (const float*)d_in[8];
    const float* bi    = (const float*)d_in[9];
    const float* mi    = (const float*)d_in[10];
    const float* vi    = (const float*)d_in[11];
    const float* wconv = (const float*)d_in[12];
    const float* gc    = (const float*)d_in[13];
    const float* bc    = (const float*)d_in[14];
    const float* mc    = (const float*)d_in[15];
    const float* vc    = (const float*)d_in[16];
    const float* wmap  = (const float*)d_in[17];
    const float* bmap  = (const float*)d_in[18];
    const float* gm    = (const float*)d_in[19];
    const float* bm    = (const float*)d_in[20];
    const float* mmn   = (const float*)d_in[21];
    const float* vm    = (const float*)d_in[22];

    float* wsf   = (float*)d_ws;
    bf16*  wfrag = (bf16*)((char*)d_ws + WFRAG_BYTE);
    bf16*  tg    = (bf16*)((char*)d_ws + TG_BYTE);
    bf16*  zt    = (bf16*)((char*)d_ws + ZT_BYTE);
    v4s*   xbf   = (v4s*)((char*)d_ws + XBF_BYTE);
    float* out   = (float*)d_out;

    hipLaunchKernelGGL(k_pre, dim3(64 + NPIX / 64), dim3(256), 0, stream,
                       x, wred, gr, br, mr, vr, wspan, bspan, gi, bi, mi, vi,
                       wconv, gc, bc, mc, vc, wmap, bmap, gm, bm, mmn, vm,
                       wsf, wfrag, tg, xbf);
    hipLaunchKernelGGL(k_inv3, dim3(12, 12, 16), dim3(256), 0, stream,
                       xbf, wsf, tg, zt);
    hipLaunchKernelGGL(k_out3, dim3(NPIX / 16), dim3(256), 0, stream,
                       zt, wsf, wfrag, out);
}

// Round 10
// 142.700 us; speedup vs baseline: 1.0431x; 1.0104x over previous
//
#include <hip/hip_runtime.h>
#include <hip/hip_bf16.h>
#include <math.h>

typedef __hip_bfloat16 bf16;
typedef __attribute__((ext_vector_type(8))) short v8s;   // 8 x bf16
typedef __attribute__((ext_vector_type(4))) short v4s;   // 4 x bf16 (8 B)
typedef __attribute__((ext_vector_type(4))) float v4f;

#define HD 96
#define WD 96
#define HW 9216            // 96*96
#define BATCH 4
#define NPIX (BATCH * HW)  // 36864

// ws layout
#define OFF_WR    0        // 16x64  scaled w_reduce (fp32)
#define OFF_CR    1024     // 16     reduce-BN additive
#define OFF_WSP   1040     // 196x16 w_span
#define OFF_BSP   4176     // 196    b_span
#define OFF_SI    4372     // 64     bn_i scale
#define OFF_CI    4436     // 64     bn_i additive
#define OFF_BIAS  4500     // 128    combined bias (fp32)
#define WFRAG_BYTE 18512   // bf16 W MFMA A-frags [mt8][ks4][lane64][j8] (32KB)
#define TG_BYTE   51328    // bf16 t buffer [NPIX][16] (1.18 MB)
#define ZT_BYTE   1230976  // bf16 zt64 [NPIX][64] (4.72 MB) - x1 channels only
#define XBF_BYTE  5949568  // bf16 x copy [b][cq16][hw][4] (4.72 MB)

__device__ __forceinline__ float geluf(float v) {
    return 0.5f * v * (1.0f + erff(v * 0.7071067811865475f));
}
__device__ __forceinline__ float upbf(short s) {
    unsigned int uu = ((unsigned int)(unsigned short)s) << 16;
    return __builtin_bit_cast(float, uu);
}
__device__ __forceinline__ v4f up4(v4s s) {
    v4f r;
    #pragma unroll
    for (int i = 0; i < 4; ++i) r[i] = upbf(s[i]);
    return r;
}
__device__ __forceinline__ short pkbf(float f) {
    return (short)__bfloat16_as_ushort(__float2bfloat16(f));
}

// ---------------- K0: param fold (blocks 0-63) + t-GEMM + xbf copy ---------
__global__ __launch_bounds__(256) void k_pre(
    const float* __restrict__ x,
    const float* __restrict__ wred,
    const float* __restrict__ gr, const float* __restrict__ br,
    const float* __restrict__ mr, const float* __restrict__ vr,
    const float* __restrict__ wspan, const float* __restrict__ bspan,
    const float* __restrict__ gi, const float* __restrict__ bi,
    const float* __restrict__ mi, const float* __restrict__ vi,
    const float* __restrict__ wconv,
    const float* __restrict__ gc, const float* __restrict__ bc,
    const float* __restrict__ mc, const float* __restrict__ vc,
    const float* __restrict__ wmap, const float* __restrict__ bmap,
    const float* __restrict__ gm, const float* __restrict__ bm,
    const float* __restrict__ mmn, const float* __restrict__ vm,
    float* __restrict__ wsf, bf16* __restrict__ wfrag,
    bf16* __restrict__ tg, v4s* __restrict__ xbf)
{
    const int tid = threadIdx.x;
    const int blk = blockIdx.x;

    if (blk < 64) {
        const int gt = blk * 256 + tid;   // 0..16383
        if (gt < 1024) {
            int r = gt >> 6;
            float sr = gr[r] * rsqrtf(vr[r] + 1e-5f);
            wsf[OFF_WR + gt] = sr * wred[gt];
        }
        if (gt < 16) {
            float sr = gr[gt] * rsqrtf(vr[gt] + 1e-5f);
            wsf[OFF_CR + gt] = br[gt] - mr[gt] * sr;
        }
        if (gt < 3136) wsf[OFF_WSP + gt] = wspan[gt];
        if (gt < 196)  wsf[OFF_BSP + gt] = bspan[gt];
        if (gt < 64) {
            float si = gi[gt] * rsqrtf(vi[gt] + 1e-5f);
            wsf[OFF_SI + gt] = si;
            wsf[OFF_CI + gt] = bi[gt] - mi[gt] * si;
        }
        if (gt < 128) {
            float sc = gc[gt] * rsqrtf(vc[gt] + 1e-5f);
            float sm = gm[gt] * rsqrtf(vm[gt] + 1e-5f);
            wsf[OFF_BIAS + gt] = (bc[gt] - mc[gt] * sc)
                               + sm * bmap[gt]
                               + (bm[gt] - mmn[gt] * sm);
        }
        // W MFMA A-fragments: lane l holds W[mt*16+(l&15)][ks*32+(l>>4)*8+j]
        {
            int j    = gt & 7;
            int lane = (gt >> 3) & 63;
            int ks   = (gt >> 9) & 3;
            int mt   = gt >> 11;
            int m = mt * 16 + (lane & 15);
            int k = ks * 32 + (lane >> 4) * 8 + j;
            float v;
            if (k < 64) {
                float sc = gc[m] * rsqrtf(vc[m] + 1e-5f);
                v = sc * wconv[m * 64 + k];
            } else {
                float sm = gm[m] * rsqrtf(vm[m] + 1e-5f);
                v = sm * wmap[m * 64 + (k - 64)];
            }
            wfrag[gt] = __float2bfloat16(v);
        }
        return;
    }

    // ---- t = ReLU(BN(w_reduce · x)) per pixel; also emit bf16 x copy ----
    __shared__ float wrl[1024];
    __shared__ float crl[16];
    for (int i = tid; i < 1024; i += 256) {
        int r = i >> 6;
        wrl[i] = gr[r] * rsqrtf(vr[r] + 1e-5f) * wred[i];
    }
    if (tid < 16)
        crl[tid] = br[tid] - mr[tid] * gr[tid] * rsqrtf(vr[tid] + 1e-5f);
    __syncthreads();

    const int p = tid & 63, u = tid >> 6;     // u wave-uniform
    const int gpix = (blk - 64) * 64 + p;     // 64-aligned, no b straddle
    const int b = gpix / HW, hw = gpix % HW;
    const float* xb = x + (size_t)b * 64 * HW + hw;
    v4s* xbf_b = xbf + (size_t)b * 16 * HW;

    float t4[4];
    #pragma unroll
    for (int r = 0; r < 4; ++r) t4[r] = crl[u * 4 + r];
    #pragma unroll 4
    for (int c4 = 0; c4 < 16; ++c4) {
        float xc0 = xb[(size_t)(c4 * 4 + 0) * HW];
        float xc1 = xb[(size_t)(c4 * 4 + 1) * HW];
        float xc2 = xb[(size_t)(c4 * 4 + 2) * HW];
        float xc3 = xb[(size_t)(c4 * 4 + 3) * HW];
        #pragma unroll
        for (int r = 0; r < 4; ++r) {
            v4f w = *(const v4f*)&wrl[(u * 4 + r) * 64 + c4 * 4];
            t4[r] += w[0] * xc0 + w[1] * xc1 + w[2] * xc2 + w[3] * xc3;
        }
        if ((c4 >> 2) == u) {                 // wave-uniform: this wave owns c4
            v4s xv;
            xv[0] = pkbf(xc0); xv[1] = pkbf(xc1);
            xv[2] = pkbf(xc2); xv[3] = pkbf(xc3);
            xbf_b[(size_t)c4 * HW + hw] = xv;
        }
    }
    v4s pk;
    #pragma unroll
    for (int r = 0; r < 4; ++r) pk[r] = pkbf(fmaxf(t4[r], 0.0f));
    *(v4s*)((short*)tg + (size_t)gpix * 16 + u * 4) = pk;
}

// ---------------- K1: involution + bn_i + GELU -> zt64 ---------------------
// Block: 256 threads = 64 pixels (8x8 tile) x 4 channel-quads of ONE group.
// Grid (12,12,16). Halo staged from pre-packed bf16 xbf. LDS 18.8 KB.
__global__ __launch_bounds__(256) void k_inv3(
    const v4s* __restrict__ xbf, const float* __restrict__ wsf,
    const bf16* __restrict__ tg, bf16* __restrict__ zt64)
{
    __shared__ v4s   xh[4 * 196];   // [quad4][pos196] bf16x4    6272 B
    __shared__ float ksh[49 * 64];  // [kk][px]                 12544 B

    const int tid = threadIdx.x;
    const int bz  = blockIdx.z;
    const int b   = bz >> 2, g = bz & 3;
    const int ty  = blockIdx.y * 8, tx = blockIdx.x * 8;

    const v4s* xbf_b = xbf + (size_t)b * 16 * HW;

    // ---- stage own-group 14x14 halo: direct b64 copies ----
    for (int it = tid; it < 784; it += 256) {        // it = qc*196 + pos
        int qc = it / 196, pos = it % 196;
        int py = pos / 14, px = pos % 14;
        int gy = ty + py - 3, gx = tx + px - 3;
        v4s v = (v4s){0, 0, 0, 0};
        if (gy >= 0 && gy < HD && gx >= 0 && gx < WD)
            v = xbf_b[(size_t)(g * 4 + qc) * HW + gy * WD + gx];
        xh[it] = v;
    }

    // ---- kern (independent of halo): read t, compute ksh ----
    const int p  = tid & 63;
    const int u  = __builtin_amdgcn_readfirstlane(tid >> 6);  // wave-uniform
    const int py0 = p >> 3, px0 = p & 7;
    const int hw  = (ty + py0) * WD + (tx + px0);
    const int gpix = b * HW + hw;

    const v8s* tp = (const v8s*)((const short*)tg + (size_t)gpix * 16);
    v8s t01 = tp[0], t23 = tp[1];
    float tr[16];
    #pragma unroll
    for (int i = 0; i < 8; ++i) { tr[i] = upbf(t01[i]); tr[8 + i] = upbf(t23[i]); }

    for (int kk = u; kk < 49; kk += 4) {
        int row = g * 49 + kk;                       // wave-uniform -> s_load
        float kv = wsf[OFF_BSP + row];
        #pragma unroll
        for (int r = 0; r < 16; ++r) kv += wsf[OFF_WSP + row * 16 + r] * tr[r];
        ksh[kk * 64 + p] = kv;
    }
    __syncthreads();

    // ---- involution accumulate: 4 channels per thread ----
    float acc[4] = {0.f, 0.f, 0.f, 0.f};
    #pragma unroll 1
    for (int i = 0; i < 7; ++i) {
        const int rowb = u * 196 + (py0 + i) * 14 + px0;
        float kr[7];
        #pragma unroll
        for (int j = 0; j < 7; ++j) kr[j] = ksh[(i * 7 + j) * 64 + p];
        #pragma unroll
        for (int j = 0; j < 7; ++j) {
            v4f xv = up4(xh[rowb + j]);
            acc[0] += kr[j] * xv[0];
            acc[1] += kr[j] * xv[1];
            acc[2] += kr[j] * xv[2];
            acc[3] += kr[j] * xv[3];
        }
    }

    // ---- bn_i + GELU, pack into zt64 (x1 channels only) ----
    const int c0 = g * 16 + u * 4;
    v4s pk1;
    #pragma unroll
    for (int ci = 0; ci < 4; ++ci) {
        float v = acc[ci] * wsf[OFF_SI + c0 + ci] + wsf[OFF_CI + c0 + ci];
        pk1[ci] = pkbf(geluf(v));
    }
    *(v4s*)&zt64[(size_t)gpix * 64 + c0] = pk1;
}

// ---------------- K2: 128x128 pointwise GEMM + GELU via MFMA ---------------
// Block: 256 threads = 4 waves; 32 px/block. Wave (pg,mh): 16 px x 64 rows.
// B-frags: ks 0,1 from zt64; ks 2,3 assembled from xbf. Grid 1152.
__global__ __launch_bounds__(256) void k_out4(
    const bf16* __restrict__ zt64, const v4s* __restrict__ xbf,
    const float* __restrict__ wsf, const bf16* __restrict__ wfrag,
    float* __restrict__ out)
{
    const int tid  = threadIdx.x;
    const int lane = tid & 63;
    const int wv   = tid >> 6;
    const int pg   = wv >> 1;              // 16-px half of the tile
    const int mh   = wv & 1;               // 64-row half of M
    const int n    = lane & 15;
    const int quad = lane >> 4;

    const int pxg = blockIdx.x * 32 + pg * 16 + n;   // global pixel
    const int b   = pxg / HW;
    const int hw  = pxg % HW;

    // B fragments ks=0,1 from zt64 row (64 bf16 = 8 v8s)
    const v8s* zb = (const v8s*)(zt64 + (size_t)pxg * 64);
    v8s bfr[4];
    bfr[0] = zb[quad];
    bfr[1] = zb[4 + quad];
    // ks=2,3 from xbf: ch-64 = (ks-2)*32 + quad*8 + j  ->  cq = (ks-2)*8 + 2*quad + j/4
    const v4s* xq = xbf + (size_t)b * 16 * HW + hw;
    #pragma unroll
    for (int ks2 = 0; ks2 < 2; ++ks2) {
        v4s a = xq[(size_t)(ks2 * 8 + 2 * quad) * HW];
        v4s c = xq[(size_t)(ks2 * 8 + 2 * quad + 1) * HW];
        v8s r;
        #pragma unroll
        for (int j = 0; j < 4; ++j) { r[j] = a[j]; r[4 + j] = c[j]; }
        bfr[2 + ks2] = r;
    }

    const v8s* wf = (const v8s*)wfrag;
    v4f acc[4];
    #pragma unroll
    for (int m = 0; m < 4; ++m) acc[m] = (v4f){0.f, 0.f, 0.f, 0.f};

    #pragma unroll
    for (int ks = 0; ks < 4; ++ks) {
        #pragma unroll
        for (int m = 0; m < 4; ++m) {
            int mt = mh * 4 + m;
            v8s afrag = wf[(mt * 4 + ks) * 64 + lane];
            acc[m] = __builtin_amdgcn_mfma_f32_16x16x32_bf16(afrag, bfr[ks], acc[m], 0, 0, 0);
        }
    }

    #pragma unroll
    for (int m = 0; m < 4; ++m) {
        int m0 = (mh * 4 + m) * 16 + quad * 4;
        v4f bs = *(const v4f*)&wsf[OFF_BIAS + m0];
        #pragma unroll
        for (int reg = 0; reg < 4; ++reg) {
            float v = acc[m][reg] + bs[reg];
            out[((size_t)(b * 128 + m0 + reg)) * HW + hw] = geluf(v);
        }
    }
}

// ---------------------------------------------------------------------------
extern "C" void kernel_launch(void* const* d_in, const int* in_sizes, int n_in,
                              void* d_out, int out_size, void* d_ws, size_t ws_size,
                              hipStream_t stream)
{
    const float* x     = (const float*)d_in[0];
    const float* wred  = (const float*)d_in[1];
    const float* gr    = (const float*)d_in[2];
    const float* br    = (const float*)d_in[3];
    const float* mr    = (const float*)d_in[4];
    const float* vr    = (const float*)d_in[5];
    const float* wspan = (const float*)d_in[6];
    const float* bspan = (const float*)d_in[7];
    const float* gi    = (const float*)d_in[8];
    const float* bi    = (const float*)d_in[9];
    const float* mi    = (const float*)d_in[10];
    const float* vi    = (const float*)d_in[11];
    const float* wconv = (const float*)d_in[12];
    const float* gc    = (const float*)d_in[13];
    const float* bc    = (const float*)d_in[14];
    const float* mc    = (const float*)d_in[15];
    const float* vc    = (const float*)d_in[16];
    const float* wmap  = (const float*)d_in[17];
    const float* bmap  = (const float*)d_in[18];
    const float* gm    = (const float*)d_in[19];
    const float* bm    = (const float*)d_in[20];
    const float* mmn   = (const float*)d_in[21];
    const float* vm    = (const float*)d_in[22];

    float* wsf   = (float*)d_ws;
    bf16*  wfrag = (bf16*)((char*)d_ws + WFRAG_BYTE);
    bf16*  tg    = (bf16*)((char*)d_ws + TG_BYTE);
    bf16*  zt64  = (bf16*)((char*)d_ws + ZT_BYTE);
    v4s*   xbf   = (v4s*)((char*)d_ws + XBF_BYTE);
    float* out   = (float*)d_out;

    hipLaunchKernelGGL(k_pre, dim3(64 + NPIX / 64), dim3(256), 0, stream,
                       x, wred, gr, br, mr, vr, wspan, bspan, gi, bi, mi, vi,
                       wconv, gc, bc, mc, vc, wmap, bmap, gm, bm, mmn, vm,
                       wsf, wfrag, tg, xbf);
    hipLaunchKernelGGL(k_inv3, dim3(12, 12, 16), dim3(256), 0, stream,
                       xbf, wsf, tg, zt64);
    hipLaunchKernelGGL(k_out4, dim3(NPIX / 32), dim3(256), 0, stream,
                       zt64, xbf, wsf, wfrag, out);
}